// Round 15
// baseline (77.643 us; speedup 1.0000x reference)
//
#include <hip/hip_runtime.h>
#include <hip/hip_bf16.h>
#include <math.h>

// DotProductAttention B=32, L=2048, D=64, fp32 IO, per-batch key-length mask.
// Round 15: 32x32 MFMA rewrite -- each wave owns 32 q-rows; softmax fully
// in-lane (guide SB's 8-warp 32x32 structure, adapted to 4 waves/QBLK=128).
//  - QK^T: mfma_f32_32x32x16_bf16(K,Q) -> S[k][q], col=q=lane&31 (m74/m101
//    layout). Lane's 32 S-regs = one q-row's k-half pair; row max/sum =
//    31 in-lane ops + 1 shfl_xor(32). m,l,corr,1/l are per-lane scalars.
//  - PV as O^T = V^T * P^T: acc col=q matches lane -> in-lane rescale.
//    P B-frags packed in-register: 4 pk2 + 4 shfl_xor(32) + 4 selects per
//    kappa-step (frag[c] = reg-group 2(c&1)+hi packs from both halves).
//  - kvimg frag-ordered for 32x32 A-frags (all ds_read_b128, conflict-free),
//    DMA'd via global_load_lds; triple-buffer + QK^T(t+1) overlap (r13/14).
//  - LPT queue, tickets 512 (QBLK 128), GRID 384, defer-max, exp2 domain.

#define BB 32
#define LL 2048
#define DD 64
#define QBLK 128
#define KBLK 64
#define NTICKETS (BB * (LL / QBLK))   // 512
#define GRID 384

typedef __attribute__((ext_vector_type(8))) short bf16x8;
typedef __attribute__((ext_vector_type(16))) float f32x16;

static __device__ __forceinline__ short f2bf(float f) {
    __hip_bfloat16 h = __float2bfloat16(f);
    return *reinterpret_cast<short*>(&h);
}
static __device__ __forceinline__ unsigned pk2(float a, float b) {
    return (unsigned)(unsigned short)f2bf(a) | ((unsigned)(unsigned short)f2bf(b) << 16);
}
static __device__ __forceinline__ float exp2c(float x) {
    return __builtin_amdgcn_exp2f(x);
}
static __device__ __forceinline__ f32x16 mfma32(bf16x8 a, bf16x8 b, f32x16 c) {
    return __builtin_amdgcn_mfma_f32_32x32x16_bf16(a, b, c, 0, 0, 0);
}

// 16B global->LDS copy (HW DMA; LDS dst = uniform base + lane*16).
static __device__ __forceinline__ void cp16(const char* g, char* lbase, int lane) {
#if __has_builtin(__builtin_amdgcn_global_load_lds)
    __builtin_amdgcn_global_load_lds(
        (__attribute__((address_space(1))) void*)g,
        (__attribute__((address_space(3))) void*)lbase, 16, 0, 0);
#else
    *reinterpret_cast<uint4*>(lbase + lane * 16) = *reinterpret_cast<const uint4*>(g);
#endif
}

// ws[0] = queue counter; ws[1..32] = batch ids sorted by valid_len desc (LPT)
__global__ void init_ctr_kernel(const int* __restrict__ vlen, int* __restrict__ ws) {
    int t = threadIdx.x;
    if (t == 0) ws[0] = 0;
    if (t < BB) {
        int v = vlen[t];
        int rank = 0;
        for (int j = 0; j < BB; ++j) {
            int vj = vlen[j];
            rank += (vj > v) || (vj == v && j < t);
        }
        ws[1 + rank] = t;
    }
}

// K,V fp32 -> bf16 frag-ordered images for 32x32 MFMA (16KB per (b,kt) tile):
//  [0,8KB):  K A-frags: entry e=(kh*4+c)*64+L holds
//            K[kh*32+(L&31)][16c+8*(L>>5) .. +7]         (bf16x8, 16B)
//  [8,16KB): V^T A-frags: entry e=(n*4+c)*64+L holds
//            V[16c+8*(L>>5)+j][32n+(L&31)], j=0..7       (bf16x8, 16B)
__global__ __launch_bounds__(256) void convert_kv_kernel(
    const float* __restrict__ K, const float* __restrict__ V,
    unsigned short* __restrict__ kv)
{
    const int tile = blockIdx.x;         // b*32 + kt
    const int tid  = threadIdx.x;
    const float* Kt = K + (size_t)tile * (KBLK * DD);
    const float* Vt = V + (size_t)tile * (KBLK * DD);
    unsigned short* img = kv + (size_t)tile * 8192;   // 16KB

    // K-frags: 512 x 16B entries, row-slices of K
    #pragma unroll
    for (int g = 0; g < 2; ++g) {
        int e = tid + g * 256;
        int f = e >> 6, L = e & 63;
        int kh = f >> 2, c = f & 3;
        int krow = kh * 32 + (L & 31);
        int dbase = 16 * c + 8 * (L >> 5);
        const float4* src = reinterpret_cast<const float4*>(Kt + krow * DD + dbase);
        float4 a = src[0], b = src[1];
        uint4 w;
        w.x = pk2(a.x, a.y); w.y = pk2(a.z, a.w);
        w.z = pk2(b.x, b.y); w.w = pk2(b.z, b.w);
        *reinterpret_cast<uint4*>(img + (size_t)e * 8) = w;
    }

    // V^T-frags: 512 x 16B entries, column-slices of V (8 consecutive k)
    unsigned short* img2 = img + 4096;
    #pragma unroll
    for (int g = 0; g < 2; ++g) {
        int e = tid + g * 256;
        int f = e >> 6, L = e & 63;
        int n = f >> 2, c = f & 3;
        int col = 32 * n + (L & 31);
        int kbase = 16 * c + 8 * (L >> 5);
        float v[8];
        #pragma unroll
        for (int j = 0; j < 8; ++j) v[j] = Vt[(kbase + j) * DD + col];
        uint4 w;
        w.x = pk2(v[0], v[1]); w.y = pk2(v[2], v[3]);
        w.z = pk2(v[4], v[5]); w.w = pk2(v[6], v[7]);
        *reinterpret_cast<uint4*>(img2 + (size_t)e * 8) = w;
    }
}

__global__ __launch_bounds__(256, 2) void attn_mfma_kernel(
    const float* __restrict__ Q, const int* __restrict__ vlen,
    const unsigned short* __restrict__ kvimg,
    float* __restrict__ O, int* __restrict__ ws)
{
    __shared__ __align__(16) unsigned short Buf[3][8192];   // 3 x 16KB (K|V^T frags)
    __shared__ int s_tile;

    int* ctr = ws;
    const int* order = ws + 1;

    const int tid  = threadIdx.x;
    const int wid  = tid >> 6;      // 0..3
    const int lane = tid & 63;
    const int l31  = lane & 31;     // this lane's q (and d) column
    const int hi   = lane >> 5;     // half-wave id

    const float QSCALE = 0.125f * 1.44269504088896341f;  // 1/sqrt(D) * log2(e)

    for (;;) {
        __syncthreads();                 // prev ticket fully done before reuse
        if (tid == 0) s_tile = atomicAdd(ctr, 1);
        __syncthreads();
        const int tile = s_tile;
        if (tile >= NTICKETS) break;

        const int b     = order[tile >> 4];   // LPT: longest batches first
        const int qt    = tile & 15;
        const int qbase = qt * QBLK + wid * 32;   // wave's 32-q base
        const int valid = vlen[b];
        const int ntiles = (valid + KBLK - 1) / KBLK;

        const unsigned short* tbase = kvimg + (size_t)b * (32 * 8192);

        // stage tile t (16KB image) into Buf[bi]: 4 x cp16 per thread
        auto dma = [&](int t, int bi) {
            const char* g = (const char*)(tbase + (size_t)t * 8192)
                            + wid * 4096 + lane * 16;
            char* l = (char*)&Buf[bi][0] + wid * 4096;
            cp16(g,        l,        lane);
            cp16(g + 1024, l + 1024, lane);
            cp16(g + 2048, l + 2048, lane);
            cp16(g + 3072, l + 3072, lane);
        };

        // ---- Q B-frags: qf[c] = Q[qbase+l31][16c+8hi .. +7] * QSCALE
        bf16x8 qf[4];
        {
            const float* Qr = Q + ((size_t)b * LL + qbase + l31) * DD;
            #pragma unroll
            for (int c = 0; c < 4; ++c) {
                const float4* p4 = reinterpret_cast<const float4*>(Qr + 16 * c + 8 * hi);
                float4 a = p4[0], d = p4[1];
                bf16x8 f;
                f[0] = f2bf(a.x * QSCALE); f[1] = f2bf(a.y * QSCALE);
                f[2] = f2bf(a.z * QSCALE); f[3] = f2bf(a.w * QSCALE);
                f[4] = f2bf(d.x * QSCALE); f[5] = f2bf(d.y * QSCALE);
                f[6] = f2bf(d.z * QSCALE); f[7] = f2bf(d.w * QSCALE);
                qf[c] = f;
            }
        }

        // acc[n][r]: O^T value at d = 32n + (r&3)+8*(r>>2)+4hi, q = l31
        f32x16 acc[2];
        #pragma unroll
        for (int i = 0; i < 16; ++i) { acc[0][i] = 0.f; acc[1][i] = 0.f; }
        float m_ = -1e30f, l_ = 0.f;    // per-lane scalars for q = l31

        // swapped QK^T: s[kh][r] = S[k = kt*64 + kh*32 + (r&3)+8*(r>>2)+4hi][q=l31]
        auto qkt = [&](int bi, f32x16* s) {
            const unsigned short* kb = &Buf[bi][0];
            __builtin_amdgcn_s_setprio(1);
            #pragma unroll
            for (int kh = 0; kh < 2; ++kh) {
                f32x16 a;
                #pragma unroll
                for (int i = 0; i < 16; ++i) a[i] = 0.f;
                #pragma unroll
                for (int c = 0; c < 4; ++c) {
                    bf16x8 kf = *reinterpret_cast<const bf16x8*>(
                        &kb[(size_t)(kh * 4 + c) * 512 + lane * 8]);
                    a = mfma32(kf, qf[c], a);
                }
                s[kh] = a;
            }
            __builtin_amdgcn_s_setprio(0);
        };

        // softmax(t) + PV(t)
        auto smpv = [&](int kt, f32x16* s, int bi) {
            const bool tail = (kt == ntiles - 1) && (valid & (KBLK - 1));
            if (tail) {
                #pragma unroll
                for (int kh = 0; kh < 2; ++kh)
                    #pragma unroll
                    for (int r = 0; r < 16; ++r) {
                        int kg = kt * KBLK + kh * 32 + (r & 3) + 8 * (r >> 2) + 4 * hi;
                        if (kg >= valid) s[kh][r] = -1e30f;
                    }
            }
            // in-lane row max (this lane's q), + cross-half combine
            float mx = s[0][0];
            #pragma unroll
            for (int r = 1; r < 16; ++r) mx = fmaxf(mx, s[0][r]);
            #pragma unroll
            for (int r = 0; r < 16; ++r) mx = fmaxf(mx, s[1][r]);
            mx = fmaxf(mx, __shfl_xor(mx, 32, 64));

            if (__any(mx - m_ > 8.0f)) {          // defer-max (T13)
                float mnew = fmaxf(m_, mx);
                float corr = exp2c(m_ - mnew);
                m_ = mnew;
                l_ *= corr;
                #pragma unroll
                for (int i = 0; i < 16; ++i) { acc[0][i] *= corr; acc[1][i] *= corr; }
            }

            float ls = 0.f;
            #pragma unroll
            for (int kh = 0; kh < 2; ++kh)
                #pragma unroll
                for (int r = 0; r < 16; ++r) {
                    float p = exp2c(s[kh][r] - m_);
                    s[kh][r] = p;
                    ls += p;
                }
            ls += __shfl_xor(ls, 32, 64);
            l_ += ls;

            // ---- P B-frags: pf[c] = P[k=16c+8hi+j][q=l31], j=0..7.
            // Lane holds k32=(r&3)+8*(r>>2)+4hi; reg group g=4g..4g+3 is
            // k32=8g+4hi+{0..3}. frag[c] needs groups g=2(c&1)+{0,1} from
            // both halves -> pack own, shfl_xor(32), select by hi.
            bf16x8 pf[4];
            #pragma unroll
            for (int c = 0; c < 4; ++c) {
                const int T = c >> 1;
                const int b0 = 8 * (c & 1);        // regs of group g=2cc
                unsigned A0 = pk2(s[T][b0 + 0], s[T][b0 + 1]);
                unsigned A1 = pk2(s[T][b0 + 2], s[T][b0 + 3]);
                unsigned B0 = pk2(s[T][b0 + 4], s[T][b0 + 5]);   // group g=2cc+1
                unsigned B1 = pk2(s[T][b0 + 6], s[T][b0 + 7]);
                unsigned xA0 = (unsigned)__shfl_xor((int)A0, 32, 64);
                unsigned xA1 = (unsigned)__shfl_xor((int)A1, 32, 64);
                unsigned xB0 = (unsigned)__shfl_xor((int)B0, 32, 64);
                unsigned xB1 = (unsigned)__shfl_xor((int)B1, 32, 64);
                union { uint4 u; bf16x8 v; } fr;
                fr.u.x = hi ? xB0 : A0;
                fr.u.y = hi ? xB1 : A1;
                fr.u.z = hi ? B0 : xA0;
                fr.u.w = hi ? B1 : xA1;
                pf[c] = fr.v;
            }

            // ---- PV: O^T = V^T * P^T; acc col=q=l31
            const unsigned short* vb = &Buf[bi][4096];
            __builtin_amdgcn_s_setprio(1);
            #pragma unroll
            for (int n = 0; n < 2; ++n) {
                #pragma unroll
                for (int c = 0; c < 4; ++c) {
                    bf16x8 vf = *reinterpret_cast<const bf16x8*>(
                        &vb[(size_t)(n * 4 + c) * 512 + lane * 8]);
                    acc[n] = mfma32(vf, pf[c], acc[n]);
                }
            }
            __builtin_amdgcn_s_setprio(0);
        };

        // ---- prologue: DMA tiles 0,1; QK^T(0) -> sA
        int bc = 0, bn = 1, bd = 2;
        dma(0, 0);
        if (ntiles > 1) dma(1, 1);
        __syncthreads();
        f32x16 sA[2], sB[2];
        qkt(0, sA);

        // ---- main loop, unroll-2 (sA/sB named, rule #20)
        int t = 0;
        for (; t + 2 <= ntiles; t += 2) {
            if (t + 2 < ntiles) dma(t + 2, bd);
            qkt(bn, sB);
            smpv(t, sA, bc);
            __syncthreads();
            { int x = bc; bc = bn; bn = bd; bd = x; }
            if (t + 3 < ntiles) dma(t + 3, bd);
            if (t + 2 < ntiles) qkt(bn, sA);
            smpv(t + 1, sB, bc);
            __syncthreads();
            { int x = bc; bc = bn; bn = bd; bd = x; }
        }
        if (t < ntiles) smpv(t, sA, bc);

        // ---- epilogue: per-lane 1/l; write O rows (q=l31), 8 float4 stores
        float linv = 1.f / l_;
        float* Ob = O + ((size_t)b * LL + qbase + l31) * DD;
        #pragma unroll
        for (int n = 0; n < 2; ++n) {
            #pragma unroll
            for (int u = 0; u < 4; ++u) {
                float4 o;
                o.x = acc[n][4 * u + 0] * linv;
                o.y = acc[n][4 * u + 1] * linv;
                o.z = acc[n][4 * u + 2] * linv;
                o.w = acc[n][4 * u + 3] * linv;
                *reinterpret_cast<float4*>(Ob + 32 * n + 8 * u + 4 * hi) = o;
            }
        }
    }
}

extern "C" void kernel_launch(void* const* d_in, const int* in_sizes, int n_in,
                              void* d_out, int out_size, void* d_ws, size_t ws_size,
                              hipStream_t stream) {
    const float* Q = (const float*)d_in[0];
    const float* K = (const float*)d_in[1];
    const float* V = (const float*)d_in[2];
    const int* vlen = (const int*)d_in[3];
    float* O = (float*)d_out;

    // ws: [0..1KB) queue; [1KB..) 16MB frag-ordered bf16 K/V images
    int* ws_i = (int*)d_ws;
    unsigned short* kvimg = (unsigned short*)((char*)d_ws + 1024);

    init_ctr_kernel<<<1, 64, 0, stream>>>(vlen, ws_i);
    convert_kv_kernel<<<BB * (LL / KBLK), 256, 0, stream>>>(K, V, kvimg);
    attn_mfma_kernel<<<GRID, 256, 0, stream>>>(Q, vlen, kvimg, O, ws_i);
}